// Round 6
// baseline (310.363 us; speedup 1.0000x reference)
//
#include <hip/hip_runtime.h>
#include <hip/hip_bf16.h>
#include <cstdint>

// KANLinear fused as ONE bf16 GEMM, K = 1024*8 (spline basis) + 1024 (silu) = 9216.
//   A[b, 8i+k]   = basis_k(x[b,i]);  A[b, 8192+i] = silu(x[b,i])
//   W[o, 8i+k]   = spline_weight[o,i,k];  W[o, 8192+i] = base_weight[o,i]
// out = A @ W^T  (M=8192, N=1024, K=9216), fp32 in/out, bf16 MFMA internal.
//
// R15 = R14 geometry (128x128, 256 thr, ring-3 48 KB, 2 blocks/CU, octet
// swizzle, XCD swizzle) with a NEW interleaved single-barrier schedule.
// R14 post-mortem: 3-barrier coarse ring serializes the LDS-read phase
// (~770 cy/CU/iter) against the MFMA phase (~620 cy) -> 1566 cy/iter,
// MfmaUtil 36%. Fix (m196/m218 lever = fine interleave + counted waits):
//   - stage target rotated: iter t stages tile t+2 into buf (t+2)%3,
//     NEVER the buf being read -> no WAR mid-iter barrier -> 1 barrier/iter
//     (WAR on the target: its tenant tile t-1 was fully read in iter t-1,
//     ordered by iter t-1's end barrier)
//   - counted lgkm interleave: chunk0 reads (af0,af1,bfg0-3) || STAGE ||
//     chunk1 reads (af2,af3); lgkmcnt(2) -> MFMA g0 overlaps chunk1;
//     lgkmcnt(0) -> MFMA g1. Issue order pinned by sched_barrier(0).
//   - vmcnt(4) (= one stage in flight) then s_barrier per iter: per-wave
//     vmcnt + barrier = all-waves-landed guarantee (R11-R14-proven).
//     Confirms tile t+1 for the next iter; never drains to 0 in-loop.
//   - prologue stages tiles 0,1 (order pinned); vmcnt(4) confirms tile 0.
//   - tail: stages past NT clamp to tile 0 (target never read again).

typedef short s16x8 __attribute__((ext_vector_type(8)));   // 8 bf16 in 4 VGPRs
typedef float f32x4 __attribute__((ext_vector_type(4)));

#define GK 9216
#define GN 1024
#define GI 1024
#define GM 8192

#define BK 32
#define NT 288               // GK/BK

#define BS_BLK 32768   // basis+silu: 8192*1024 threads (1 per x)
#define RP_BLK 4608    // repack   : 1024*1152 threads (8 cols each)

__device__ __forceinline__ void cp16(const __hip_bfloat16* g, __hip_bfloat16* l) {
  __builtin_amdgcn_global_load_lds((const __attribute__((address_space(1))) void*)g,
                                   (__attribute__((address_space(3))) void*)l, 16, 0, 0);
}

__device__ __forceinline__ uint32_t bfbits(float f) {   // RTNE bf16 bits, SSA only
  __hip_bfloat16 h = __float2bfloat16(f);
  unsigned short us;
  __builtin_memcpy(&us, &h, 2);
  return (uint32_t)us;
}

__device__ __forceinline__ void basis4(float xv, int& jj, float& w0, float& w1,
                                       float& w2, float& w3) {
  float t = fminf(1.f, fmaxf(-1.f, xv));
  float us = (t + 1.f) * 2.5f;          // (t - grid[3]) / h, grid[3]=-1, h=0.4
  int j = (int)us;
  if (j > 4) j = 4;                     // t==1.0 edge: matches reference exactly
  float u = us - (float)j;
  float u2 = u * u, u3 = u2 * u;
  float om = 1.f - u;
  jj = j;
  w0 = om * om * om * (1.f / 6.f);
  w1 = (3.f * u3 - 6.f * u2 + 4.f) * (1.f / 6.f);
  w2 = (-3.f * u3 + 3.f * u2 + 3.f * u + 1.f) * (1.f / 6.f);
  w3 = u3 * (1.f / 6.f);
}

// --- ONE dispatch: basis+silu (1 thread/x) + weight repack -----------------
__global__ void kan_prep_all(const float* __restrict__ x,
                             const float* __restrict__ baseW,
                             const float* __restrict__ splineW,
                             __hip_bfloat16* __restrict__ W2,
                             __hip_bfloat16* __restrict__ A) {
  int bid = blockIdx.x;
  if (bid < BS_BLK) {
    int t = bid * 256 + threadIdx.x;        // [0, 8192*1024)
    int b = t >> 10, i = t & 1023;
    float xv = x[t];

    // silu -> A[b, 8192+i], 2 B coalesced store
    float sl = xv / (1.f + __expf(-xv));
    A[(size_t)b * GK + 8192 + i] = __float2bfloat16(sl);

    // basis -> A[b, 8i..8i+7]: funnel-shift packed weights into window jj,
    // one dense 16 B store per lane (stride-16 across the wave)
    int jj; float w0, w1, w2, w3;
    basis4(xv, jj, w0, w1, w2, w3);
    uint64_t W64 = (uint64_t)(bfbits(w0) | (bfbits(w1) << 16)) |
                   ((uint64_t)(bfbits(w2) | (bfbits(w3) << 16)) << 32);
    int sh = jj * 16;                                  // 0,16,32,48,64
    uint64_t lo = (jj < 4) ? (W64 << sh) : 0ull;       // guard UB at sh=64
    uint64_t hi = (jj == 0) ? 0ull : (W64 >> (64 - sh));
    uint4 pk;
    pk.x = (uint32_t)lo;  pk.y = (uint32_t)(lo >> 32);
    pk.z = (uint32_t)hi;  pk.w = (uint32_t)(hi >> 32);
    *(uint4*)(A + (size_t)b * GK + (size_t)i * 8) = pk;
  } else {
    // repack: thread handles 8 cols (32 B fp32 in, 16 B bf16 out)
    int t = (bid - BS_BLK) * 256 + threadIdx.x;   // [0, 1024*1152)
    int o = t / 1152;
    int c = (t - o * 1152) * 8;
    const float* src = (c < 8192) ? (splineW + (size_t)o * 8192 + c)
                                  : (baseW + (size_t)o * GI + (c - 8192));
    float4 v0 = ((const float4*)src)[0];
    float4 v1 = ((const float4*)src)[1];
    uint4 pk;
    pk.x = bfbits(v0.x) | (bfbits(v0.y) << 16);
    pk.y = bfbits(v0.z) | (bfbits(v0.w) << 16);
    pk.z = bfbits(v1.x) | (bfbits(v1.y) << 16);
    pk.w = bfbits(v1.z) | (bfbits(v1.w) << 16);
    *(uint4*)(W2 + (size_t)o * GK + c) = pk;
  }
}

// --- R15 GEMM: 128x128, 256 thr, ring-3, interleaved 1-barrier schedule ----
__global__ __launch_bounds__(256, 2) void kan_gemm_il(
    const __hip_bfloat16* __restrict__ A,   // (8192, 9216) bf16
    const __hip_bfloat16* __restrict__ B,   // (1024, 9216) bf16
    float* __restrict__ C) {                // (8192, 1024) fp32
  __shared__ __align__(16) __hip_bfloat16 As[3][128 * BK];   // 3 x 8 KB
  __shared__ __align__(16) __hip_bfloat16 Bs[3][128 * BK];   // 3 x 8 KB
  const int tid = threadIdx.x;
  const int lane = tid & 63;
  const int wave = tid >> 6;                 // 0..3
  const int wm = wave >> 1, wn = wave & 1;   // 2x2 waves, 64x64 out each

  // XCD swizzle over exactly 512 WGs: xcd = linear%8 owns 64 consecutive c's
  // = 8 rowBands x 8 colBands -> A panels L2-shared x8 within the XCD.
  const int linear = blockIdx.y * 8 + blockIdx.x;       // 0..511
  const int c = (linear & 7) * 64 + (linear >> 3);
  const int colBand = c & 7;                 // 0..7
  const int rowBand = c >> 3;                // 0..63
  const int blockRow = rowBand * 128;
  const int blockCol = colBand * 128;

  // staging: per cp16, 256 lanes x 16 B = 4 KB = 64 rows x 32 k, linear LDS.
  // k-octet XOR swizzle on the GLOBAL side (R13/R14-verified, conflicts = 0):
  // thread (srow,sq) loads octet sq ^ ((srow>>1)&3); 64 B per 4-lane group
  // unchanged -> coalescing intact. Rows 64-127: (+64>>1)&3 == 0, same swz.
  const int srow = tid >> 2;                 // 0..63
  const int sq = tid & 3;
  const int ssw = sq ^ ((srow >> 1) & 3);    // swizzled source octet
  const __hip_bfloat16* aSrc = A + (size_t)(blockRow + srow) * GK + ssw * 8;
  const __hip_bfloat16* bSrc = B + (size_t)(blockCol + srow) * GK + ssw * 8;
  const int ldsOff = wave * 512;             // wave-uniform; HW adds lane*16 B

  // STAGE = 4 cp16: A rows 0-63, 64-127; B rows 0-63, 64-127 (4 KB each)
#define STAGE(T, BUF)                                             \
  do {                                                            \
    const __hip_bfloat16* ga = aSrc + (T) * BK;                   \
    const __hip_bfloat16* gb = bSrc + (T) * BK;                   \
    cp16(ga, As[BUF] + ldsOff);                                   \
    cp16(ga + 64 * GK, As[BUF] + ldsOff + 2048);                  \
    cp16(gb, Bs[BUF] + ldsOff);                                   \
    cp16(gb + 64 * GK, Bs[BUF] + ldsOff + 2048);                  \
  } while (0)

  const int q = lane >> 4, r16 = lane & 15;
  // frag read slot = q ^ ((row>>1)&3); wm*64/tm*16 shifts vanish mod 4
  // after >>1, so the swizzle folds into the per-lane constant base.
  const int qs = q ^ ((r16 >> 1) & 3);
  const int aBase = (wm * 64 + r16) * 4 + qs;   // s16x8 index; +tm*64
  const int bBase = (wn * 64 + r16) * 4 + qs;   // +tn*64

  f32x4 acc[4][4] = {};

  // prologue: stage tiles 0,1 (order pinned so vmcnt(4) = tile 0 landed)
  STAGE(0, 0);
  __builtin_amdgcn_sched_barrier(0);
  STAGE(1, 1);
  __builtin_amdgcn_sched_barrier(0);
  asm volatile("s_waitcnt vmcnt(4)" ::: "memory");   // own tile-0 loads done
  __builtin_amdgcn_sched_barrier(0);
  __builtin_amdgcn_s_barrier();                      // => ALL waves' tile 0 in

  for (int t3 = 0; t3 < NT / 3; ++t3) {
#pragma unroll
    for (int u = 0; u < 3; ++u) {
      const int t = t3 * 3 + u;
      // stage tile t+2 into buf (t+2)%3 — never the buf being read.
      // tail: clamp to tile 0 (that target is never read again).
      const int tp = (t + 2 < NT) ? (t + 2) : 0;
      const int w = (u + 2) % 3;               // compile-time in unrolled body
      const s16x8* Af = (const s16x8*)As[u];
      const s16x8* Bf = (const s16x8*)Bs[u];
      s16x8 af[4], bfg[4];
      // chunk0: af0, af1, all B-frags (6 ds_read_b128)
      af[0] = Af[aBase];
      af[1] = Af[aBase + 64];
#pragma unroll
      for (int tn = 0; tn < 4; ++tn) bfg[tn] = Bf[bBase + tn * 64];
      __builtin_amdgcn_sched_barrier(0);
      STAGE(tp, w);                            // early issue, lands next+1 iter
      __builtin_amdgcn_sched_barrier(0);
      // chunk1: af2, af3 (2 ds_read_b128)
      af[2] = Af[aBase + 128];
      af[3] = Af[aBase + 192];
      asm volatile("s_waitcnt lgkmcnt(2)" ::: "memory");   // chunk0 landed
      __builtin_amdgcn_sched_barrier(0);
      __builtin_amdgcn_s_setprio(1);
#pragma unroll
      for (int tm = 0; tm < 2; ++tm)           // MFMA g0 overlaps chunk1
#pragma unroll
        for (int tn = 0; tn < 4; ++tn)
          acc[tm][tn] = __builtin_amdgcn_mfma_f32_16x16x32_bf16(
              af[tm], bfg[tn], acc[tm][tn], 0, 0, 0);
      __builtin_amdgcn_s_setprio(0);
      asm volatile("s_waitcnt lgkmcnt(0)" ::: "memory");   // chunk1 landed
      __builtin_amdgcn_sched_barrier(0);
      __builtin_amdgcn_s_setprio(1);
#pragma unroll
      for (int tm = 2; tm < 4; ++tm)           // MFMA g1
#pragma unroll
        for (int tn = 0; tn < 4; ++tn)
          acc[tm][tn] = __builtin_amdgcn_mfma_f32_16x16x32_bf16(
              af[tm], bfg[tn], acc[tm][tn], 0, 0, 0);
      __builtin_amdgcn_s_setprio(0);
      // own stage(t+1) confirmed (leaves only stage(t+2) in flight);
      // barrier upgrades to the all-waves guarantee for the next iter.
      asm volatile("s_waitcnt vmcnt(4)" ::: "memory");
      __builtin_amdgcn_sched_barrier(0);
      __builtin_amdgcn_s_barrier();
    }
  }
  // drain the tail prefetches before LDS goes away
  asm volatile("s_waitcnt vmcnt(0)" ::: "memory");

  // C/D layout: col = lane&15, row = (lane>>4)*4 + reg  [m89-verified]
  const int cRow0 = blockRow + wm * 64 + q * 4;
  const int cCol0 = blockCol + wn * 64 + r16;
#pragma unroll
  for (int tm = 0; tm < 4; ++tm)
#pragma unroll
    for (int tn = 0; tn < 4; ++tn) {
      int col = cCol0 + tn * 16;
      size_t base = (size_t)(cRow0 + tm * 16) * GN + col;
#pragma unroll
      for (int r = 0; r < 4; ++r)
        C[base + (size_t)r * GN] = acc[tm][tn][r];
    }
#undef STAGE
}

// --- emergency fallback if ws_size is too small ----------------------------
__global__ void kan_naive(const float* __restrict__ x,
                          const float* __restrict__ bw,
                          const float* __restrict__ sw,
                          float* __restrict__ out) {
  int o = blockIdx.x * 256 + threadIdx.x;
  int b = blockIdx.y;
  float acc = 0.f;
  for (int i = 0; i < GI; ++i) {
    float xv = x[(size_t)b * GI + i];
    float sl = xv / (1.f + __expf(-xv));
    acc += sl * bw[(size_t)o * GI + i];
    int jj; float w0, w1, w2, w3;
    basis4(xv, jj, w0, w1, w2, w3);
    const float* swr = sw + ((size_t)o * GI + i) * 8 + jj;
    acc += w0 * swr[0] + w1 * swr[1] + w2 * swr[2] + w3 * swr[3];
  }
  out[(size_t)b * GN + o] = acc;
}

extern "C" void kernel_launch(void* const* d_in, const int* in_sizes, int n_in,
                              void* d_out, int out_size, void* d_ws, size_t ws_size,
                              hipStream_t stream) {
  const float* x  = (const float*)d_in[0];   // (8192, 1024) fp32
  const float* bw = (const float*)d_in[1];   // (1024, 1024) fp32
  const float* sw = (const float*)d_in[2];   // (1024, 1024, 8) fp32
  float* out = (float*)d_out;                // (8192, 1024) fp32

  const size_t wBytes = (size_t)GK * GN * 2;   // 18.9 MB repacked weights
  const size_t aBytes = (size_t)GM * GK * 2;   // 151 MB activations

  if (ws_size < wBytes + aBytes) {
    kan_naive<<<dim3(GN / 256, GM), 256, 0, stream>>>(x, bw, sw, out);
    return;
  }

  __hip_bfloat16* W2 = (__hip_bfloat16*)d_ws;
  __hip_bfloat16* Abuf = W2 + (size_t)GK * GN;       // 16B-aligned

  kan_prep_all<<<BS_BLK + RP_BLK, 256, 0, stream>>>(x, bw, sw, W2, Abuf);
  kan_gemm_il<<<dim3(GN / 128, GM / 128), 256, 0, stream>>>(Abuf, W2, out);
}

// Round 11
// 262.811 us; speedup vs baseline: 1.1809x; 1.1809x over previous
//
#include <hip/hip_runtime.h>
#include <hip/hip_bf16.h>
#include <cstdint>

// KANLinear fused as ONE bf16 GEMM, K = 1024*8 (spline basis) + 1024 (silu) = 9216.
//   A[b, 8i+k]   = basis_k(x[b,i]);  A[b, 8192+i] = silu(x[b,i])
//   W[o, 8i+k]   = spline_weight[o,i,k];  W[o, 8192+i] = base_weight[o,i]
// out = A @ W^T  (M=8192, N=1024, K=9216), fp32 in/out, bf16 MFMA internal.
//
// R20 = R19 resubmit (4th consecutive infra failure; kernel never ran).
// R16+ rationale: R11/R14/R15 all ran at ~2.2x the pipe floors with
// MfmaUtil 32-39% — every schedule issued ALL frag reads, waited lgkm,
// then ran ALL MFMAs, serializing the CU's LDS burst (~770 cy) against
// its MFMA burst (~620 cy). Fix = per-wave software pipeline: phase p
// issues phase p+1's A-reads, then MFMAs on last phase's frags (counted
// lgkmcnt(4), A-register ping-pong aA/aB).
//   - 256x256 tile, BK=64, 8 waves (2x4) of 128x64 (42.7 FLOP/LDS-byte ->
//     LDS floor 2260 cy < MFMA floor 2483 cy per K-tile: MFMA-bound)
//   - split-K=2 -> 128 tiles x 2 = 256 WGs = 1 block/CU + fp32 reduce
//   - LDS dbuf-2 x (A 256x64 + B 256x64) = 128 KB; stage t+1 during t
//     (A-units phase 0, B-units phase 1 -> youngest cp16 >=2 phases
//     before the boundary vmcnt(0): drain ~free)
//   - ONE barrier + ONE vmcnt(0) per K-tile (per 512 CU-MFMA ~2500 cy);
//     overlap is INTRA-wave, so 1 block/CU suffices (unlike R11)
//   - B frags (8 = 32 VGPR) read once per K-tile at phase 0 and held
//   - 8-slot k-octet XOR swizzle (stage octet so^(srow8&7), read slot
//     (4kk+q)^(r16&7)): slot^(row&7) = global octet; each 8-lane group
//     spans all 32 banks once -> conflict-free (R13/R14 measured 0)
//   - setprio(1) per 16-MFMA cluster; sched_barrier(0) pins issue order
//     so counted lgkm waits mean what they say (rule 18)
//   - XCD swizzle: xcd owns one ksplit-half x 8 rowBands x 4 colBands

typedef short s16x8 __attribute__((ext_vector_type(8)));   // 8 bf16 in 4 VGPRs
typedef float f32x4 __attribute__((ext_vector_type(4)));

#define GK 9216
#define GN 1024
#define GI 1024
#define GM 8192

#define KSPLIT 4608          // GK/2
#define NTK 72               // KSPLIT/64 K-tiles per block

#define BS_BLK 32768   // basis+silu: 8192*1024 threads (1 per x)
#define RP_BLK 4608    // repack   : 1024*1152 threads (8 cols each)

#define SB __builtin_amdgcn_sched_barrier(0)

__device__ __forceinline__ void cp16(const __hip_bfloat16* g, __hip_bfloat16* l) {
  __builtin_amdgcn_global_load_lds((const __attribute__((address_space(1))) void*)g,
                                   (__attribute__((address_space(3))) void*)l, 16, 0, 0);
}

__device__ __forceinline__ uint32_t bfbits(float f) {   // RTNE bf16 bits, SSA only
  __hip_bfloat16 h = __float2bfloat16(f);
  unsigned short us;
  __builtin_memcpy(&us, &h, 2);
  return (uint32_t)us;
}

__device__ __forceinline__ void basis4(float xv, int& jj, float& w0, float& w1,
                                       float& w2, float& w3) {
  float t = fminf(1.f, fmaxf(-1.f, xv));
  float us = (t + 1.f) * 2.5f;          // (t - grid[3]) / h, grid[3]=-1, h=0.4
  int j = (int)us;
  if (j > 4) j = 4;                     // t==1.0 edge: matches reference exactly
  float u = us - (float)j;
  float u2 = u * u, u3 = u2 * u;
  float om = 1.f - u;
  jj = j;
  w0 = om * om * om * (1.f / 6.f);
  w1 = (3.f * u3 - 6.f * u2 + 4.f) * (1.f / 6.f);
  w2 = (-3.f * u3 + 3.f * u2 + 3.f * u + 1.f) * (1.f / 6.f);
  w3 = u3 * (1.f / 6.f);
}

// --- ONE dispatch: basis+silu (1 thread/x) + weight repack -----------------
__global__ void kan_prep_all(const float* __restrict__ x,
                             const float* __restrict__ baseW,
                             const float* __restrict__ splineW,
                             __hip_bfloat16* __restrict__ W2,
                             __hip_bfloat16* __restrict__ A) {
  int bid = blockIdx.x;
  if (bid < BS_BLK) {
    int t = bid * 256 + threadIdx.x;        // [0, 8192*1024)
    int b = t >> 10, i = t & 1023;
    float xv = x[t];

    float sl = xv / (1.f + __expf(-xv));
    A[(size_t)b * GK + 8192 + i] = __float2bfloat16(sl);

    int jj; float w0, w1, w2, w3;
    basis4(xv, jj, w0, w1, w2, w3);
    uint64_t W64 = (uint64_t)(bfbits(w0) | (bfbits(w1) << 16)) |
                   ((uint64_t)(bfbits(w2) | (bfbits(w3) << 16)) << 32);
    int sh = jj * 16;                                  // 0,16,32,48,64
    uint64_t lo = (jj < 4) ? (W64 << sh) : 0ull;       // guard UB at sh=64
    uint64_t hi = (jj == 0) ? 0ull : (W64 >> (64 - sh));
    uint4 pk;
    pk.x = (uint32_t)lo;  pk.y = (uint32_t)(lo >> 32);
    pk.z = (uint32_t)hi;  pk.w = (uint32_t)(hi >> 32);
    *(uint4*)(A + (size_t)b * GK + (size_t)i * 8) = pk;
  } else {
    int t = (bid - BS_BLK) * 256 + threadIdx.x;   // [0, 1024*1152)
    int o = t / 1152;
    int c = (t - o * 1152) * 8;
    const float* src = (c < 8192) ? (splineW + (size_t)o * 8192 + c)
                                  : (baseW + (size_t)o * GI + (c - 8192));
    float4 v0 = ((const float4*)src)[0];
    float4 v1 = ((const float4*)src)[1];
    uint4 pk;
    pk.x = bfbits(v0.x) | (bfbits(v0.y) << 16);
    pk.y = bfbits(v0.z) | (bfbits(v0.w) << 16);
    pk.z = bfbits(v1.x) | (bfbits(v1.y) << 16);
    pk.w = bfbits(v1.z) | (bfbits(v1.w) << 16);
    *(uint4*)(W2 + (size_t)o * GK + c) = pk;
  }
}

// --- R20 GEMM: 256x256, BK=64, 8 waves, per-wave pipelined phases ----------
__global__ __launch_bounds__(512, 2) void kan_gemm_pl(
    const __hip_bfloat16* __restrict__ A,   // (8192, 9216) bf16
    const __hip_bfloat16* __restrict__ B,   // (1024, 9216) bf16
    float* __restrict__ C0,                 // ksplit 0 -> out
    float* __restrict__ C1) {               // ksplit 1 -> partial
  __shared__ __align__(16) __hip_bfloat16 As[2][16384];   // 2 x 256r x 64k = 64 KB
  __shared__ __align__(16) __hip_bfloat16 Bs[2][16384];   // 64 KB
  const int tid = threadIdx.x;
  const int lane = tid & 63;
  const int wave = tid >> 6;                 // 0..7
  const int wm = wave >> 2, wn = wave & 3;   // 2x4 waves, 128x64 out each

  // XCD swizzle, 256 WGs: xcd = linear%8 -> 32 consecutive c's
  // (xcd 0-3: ksplit 0, xcd 4-7: ksplit 1; 8 rowBands x 4 colBands each)
  const int linear = blockIdx.x;                        // 0..255
  const int c = (linear & 7) * 32 + (linear >> 3);
  const int ks = c >> 7;
  const int cc = c & 127;
  const int colBand = cc & 3;
  const int rowBand = cc >> 2;               // 0..31
  const int blockRow = rowBand * 256;
  const int blockCol = colBand * 256;
  const int kbase = ks * KSPLIT;

  // staging: per cp16-unit, 512 thr x 16 B = 16 KB = 64 rows x 64 k, linear
  // LDS. 8-slot octet swizzle on the GLOBAL side: thread (srow8, so) loads
  // octet so ^ (srow8 & 7); per-8-thread group still one 128 B global row.
  const int srow8 = tid >> 3;                // 0..63
  const int so = tid & 7;
  const int ssw = so ^ (srow8 & 7);
  const __hip_bfloat16* aSrc = A + (size_t)(blockRow + srow8) * GK + kbase + ssw * 8;
  const __hip_bfloat16* bSrc = B + (size_t)(blockCol + srow8) * GK + kbase + ssw * 8;
  const int ldsW = wave * 512;               // wave-uniform; HW adds lane*16 B

  // unit U covers tile rows U*64..U*64+63 (same for A and B)
#define STAGE_AU(U, T, NB) cp16(aSrc + (size_t)(U) * 64 * GK + (size_t)(T) * 64, \
                                As[NB] + (U) * 4096 + ldsW)
#define STAGE_BU(U, T, NB) cp16(bSrc + (size_t)(U) * 64 * GK + (size_t)(T) * 64, \
                                Bs[NB] + (U) * 4096 + ldsW)

  const int q = lane >> 4, r16 = lane & 15;
  const int swz = r16 & 7;
  const int s0 = q ^ swz;                    // kk=0 slot
  const int s1 = (4 + q) ^ swz;              // kk=1 slot
  // s16x8 index = row*8 + slot; row = w*{128,64} + m*16 + r16 (m*16 == 0 mod 8)
  const int aBase0 = (wm * 128 + r16) * 8 + s0;
  const int aBase1 = (wm * 128 + r16) * 8 + s1;
  const int bBase0 = (wn * 64 + r16) * 8 + s0;
  const int bBase1 = (wn * 64 + r16) * 8 + s1;

  f32x4 acc[8][4] = {};

  // 16 MFMA on m-pair P using A-frag set AR = {m kk0, m kk1, m+1 kk0, m+1 kk1}
#define MPAIR(P, AR)                                                          \
  do {                                                                        \
    __builtin_amdgcn_s_setprio(1);                                            \
    _Pragma("unroll")                                                         \
    for (int n = 0; n < 4; ++n) {                                             \
      acc[2*(P)][n]   = __builtin_amdgcn_mfma_f32_16x16x32_bf16(AR[0], b0[n], acc[2*(P)][n],   0, 0, 0); \
      acc[2*(P)][n]   = __builtin_amdgcn_mfma_f32_16x16x32_bf16(AR[1], b1[n], acc[2*(P)][n],   0, 0, 0); \
      acc[2*(P)+1][n] = __builtin_amdgcn_mfma_f32_16x16x32_bf16(AR[2], b0[n], acc[2*(P)+1][n], 0, 0, 0); \
      acc[2*(P)+1][n] = __builtin_amdgcn_mfma_f32_16x16x32_bf16(AR[3], b1[n], acc[2*(P)+1][n], 0, 0, 0); \
    }                                                                         \
    __builtin_amdgcn_s_setprio(0);                                            \
  } while (0)

  // prologue: stage K-tile 0 into buf 0, drain, barrier
  STAGE_AU(0, 0, 0); STAGE_AU(1, 0, 0); STAGE_AU(2, 0, 0); STAGE_AU(3, 0, 0);
  STAGE_BU(0, 0, 0); STAGE_BU(1, 0, 0); STAGE_BU(2, 0, 0); STAGE_BU(3, 0, 0);
  asm volatile("s_waitcnt vmcnt(0)" ::: "memory");
  SB;
  __builtin_amdgcn_s_barrier();

  for (int t = 0; t < NTK; ++t) {
    const int cb = t & 1, nb = cb ^ 1;
    const int tp = (t + 1 < NTK) ? (t + 1) : 0;   // tail: restage tile 0 (unread)
    const s16x8* Af = (const s16x8*)As[cb];
    const s16x8* Bf = (const s16x8*)Bs[cb];
    s16x8 b0[4], b1[4], aA[4], aB[4];

    // ---- phase 0: issue B(8) + A m01(4) + A m23(4); stage A-units; MFMA m01
#pragma unroll
    for (int n = 0; n < 4; ++n) { b0[n] = Bf[bBase0 + n * 128]; b1[n] = Bf[bBase1 + n * 128]; }
    aA[0] = Af[aBase0];        aA[1] = Af[aBase1];
    aA[2] = Af[aBase0 + 128];  aA[3] = Af[aBase1 + 128];
    SB;
    aB[0] = Af[aBase0 + 256];  aB[1] = Af[aBase1 + 256];
    aB[2] = Af[aBase0 + 384];  aB[3] = Af[aBase1 + 384];
    SB;
    STAGE_AU(0, tp, nb); STAGE_AU(1, tp, nb); STAGE_AU(2, tp, nb); STAGE_AU(3, tp, nb);
    SB;
    asm volatile("s_waitcnt lgkmcnt(4)" ::: "memory");   // B + A01 landed
    SB;
    MPAIR(0, aA);
    // ---- phase 1: issue A m45 into aA; stage B-units; MFMA m23 ----
    SB;
    aA[0] = Af[aBase0 + 512];  aA[1] = Af[aBase1 + 512];
    aA[2] = Af[aBase0 + 640];  aA[3] = Af[aBase1 + 640];
    SB;
    STAGE_BU(0, tp, nb); STAGE_BU(1, tp, nb); STAGE_BU(2, tp, nb); STAGE_BU(3, tp, nb);
    SB;
    asm volatile("s_waitcnt lgkmcnt(4)" ::: "memory");   // A23 landed
    SB;
    MPAIR(1, aB);
    // ---- phase 2: issue A m67 into aB; MFMA m45 ----
    SB;
    aB[0] = Af[aBase0 + 768];  aB[1] = Af[aBase1 + 768];
    aB[2] = Af[aBase0 + 896];  aB[3] = Af[aBase1 + 896];
    SB;
    asm volatile("s_waitcnt lgkmcnt(4)" ::: "memory");   // A45 landed
    SB;
    MPAIR(2, aA);
    // ---- phase 3: MFMA m67; K-tile boundary sync ----
    SB;
    asm volatile("s_waitcnt lgkmcnt(0)" ::: "memory");   // A67 landed
    SB;
    MPAIR(3, aB);
    // boundary: tile t+1's 8 cp16s were issued >=2 phases ago -> vmcnt(0)
    // is ~free; barrier upgrades both guarantees (reads retired, stages
    // landed) to all-waves for the next K-tile.
    asm volatile("s_waitcnt vmcnt(0)" ::: "memory");
    SB;
    __builtin_amdgcn_s_barrier();
  }

  float* __restrict__ Cd = ks ? C1 : C0;
  // C/D layout: col = lane&15, row = (lane>>4)*4 + reg  [m89-verified]
  const int cRow0 = blockRow + wm * 128 + q * 4;
  const int cCol0 = blockCol + wn * 64 + r16;
#pragma unroll
  for (int tm = 0; tm < 8; ++tm)
#pragma unroll
    for (int tn = 0; tn < 4; ++tn) {
      int col = cCol0 + tn * 16;
      size_t base = (size_t)(cRow0 + tm * 16) * GN + col;
#pragma unroll
      for (int r = 0; r < 4; ++r)
        Cd[base + (size_t)r * GN] = acc[tm][tn][r];
    }
#undef MPAIR
#undef STAGE_AU
#undef STAGE_BU
}

// --- reduce: out += partial (both fp32, 8192x1024) -------------------------
__global__ void kan_reduce(float* __restrict__ out, const float* __restrict__ part) {
  size_t i = ((size_t)blockIdx.x * 256 + threadIdx.x) * 4;
  float4 a = *(const float4*)(out + i);
  float4 b = *(const float4*)(part + i);
  a.x += b.x; a.y += b.y; a.z += b.z; a.w += b.w;
  *(float4*)(out + i) = a;
}

// --- emergency fallback if ws_size is too small ----------------------------
__global__ void kan_naive(const float* __restrict__ x,
                          const float* __restrict__ bw,
                          const float* __restrict__ sw,
                          float* __restrict__ out) {
  int o = blockIdx.x * 256 + threadIdx.x;
  int b = blockIdx.y;
  float acc = 0.f;
  for (int i = 0; i < GI; ++i) {
    float xv = x[(size_t)b * GI + i];
    float sl = xv / (1.f + __expf(-xv));
    acc += sl * bw[(size_t)o * GI + i];
    int jj; float w0, w1, w2, w3;
    basis4(xv, jj, w0, w1, w2, w3);
    const float* swr = sw + ((size_t)o * GI + i) * 8 + jj;
    acc += w0 * swr[0] + w1 * swr[1] + w2 * swr[2] + w3 * swr[3];
  }
  out[(size_t)b * GN + o] = acc;
}

extern "C" void kernel_launch(void* const* d_in, const int* in_sizes, int n_in,
                              void* d_out, int out_size, void* d_ws, size_t ws_size,
                              hipStream_t stream) {
  const float* x  = (const float*)d_in[0];   // (8192, 1024) fp32
  const float* bw = (const float*)d_in[1];   // (1024, 1024) fp32
  const float* sw = (const float*)d_in[2];   // (1024, 1024, 8) fp32
  float* out = (float*)d_out;                // (8192, 1024) fp32

  const size_t wBytes = (size_t)GK * GN * 2;   // 18.9 MB repacked weights
  const size_t aBytes = (size_t)GM * GK * 2;   // 151 MB activations
  const size_t pBytes = (size_t)GM * GN * 4;   // 33.6 MB split-K partial

  if (ws_size < wBytes + aBytes + pBytes) {
    kan_naive<<<dim3(GN / 256, GM), 256, 0, stream>>>(x, bw, sw, out);
    return;
  }

  __hip_bfloat16* W2 = (__hip_bfloat16*)d_ws;
  __hip_bfloat16* Abuf = W2 + (size_t)GK * GN;       // 16B-aligned
  float* partial = (float*)((char*)d_ws + wBytes + aBytes);

  kan_prep_all<<<BS_BLK + RP_BLK, 256, 0, stream>>>(x, bw, sw, W2, Abuf);
  kan_gemm_pl<<<dim3(256), 512, 0, stream>>>(Abuf, W2, out, partial);
  kan_reduce<<<GM * GN / (256 * 4), 256, 0, stream>>>(out, partial);
}

// Round 12
// 262.467 us; speedup vs baseline: 1.1825x; 1.0013x over previous
//
#include <hip/hip_runtime.h>
#include <hip/hip_bf16.h>
#include <cstdint>

// KANLinear fused as ONE bf16 GEMM, K = 1024*8 (spline basis) + 1024 (silu) = 9216.
//   A[b, 8i+k]   = basis_k(x[b,i]);  A[b, 8192+i] = silu(x[b,i])
//   W[o, 8i+k]   = spline_weight[o,i,k];  W[o, 8192+i] = base_weight[o,i]
// out = A @ W^T  (M=8192, N=1024, K=9216), fp32 in/out, bf16 MFMA internal.
//
// R21 = R20 (per-wave pipelined 256x256/BK=64, MEASURED 136us/48% MfmaUtil,
// total 262.8us) + cross-boundary prefetch. R20 post-mortem: the remaining
// 1.82x-over-MFMA-floor is phase 0 after each barrier: all waves issue
// 12-16 ds_reads and wait before the first MFMA (~1150 cy LDS burst, MFMA
// idle). Fix (one mechanism):
//   - boundary sync (lgkm(0)+vmcnt(0)+barrier) moved to END OF PHASE 2:
//     after it, buf nb (tile t+1) is landed for ALL waves -> tile t+1 is
//     legally readable during phase 3
//   - phase 3 prefetches next-tile b0 frags (4 ds_reads, alternating reg
//     set b0A/b0B via unroll-2) under MPAIR3's ~620 cy of MFMA
//   - MPAIR0 split into kk0/kk1 halves (lgkm(8) then lgkm(4)): first 8
//     MFMAs need only {prefetched b0 + A01} -> post-barrier exposed burst
//     1150 -> ~380 cy. b1 single reg set (dead before next issue).
//   - all 8 stage-cp16s in phase 0 (youngest ~2 MFMA-phases before the
//     boundary vmcnt(0) -> drain stays ~free)
//   - MPAIR reordered to dep-distance-8 (kk0 groups then kk1 groups)
// WAR/RAW: every buf overwrite is separated from its readers by a barrier
// at which those readers have lgkmcnt(0)'d (no timing arguments).
// Carried from R20: 8-slot octet swizzle (conflicts=0), split-K=2 + reduce,
// XCD swizzle, setprio on MFMA clusters, SB issue-order pinning (rule 18).

typedef short s16x8 __attribute__((ext_vector_type(8)));   // 8 bf16 in 4 VGPRs
typedef float f32x4 __attribute__((ext_vector_type(4)));

#define GK 9216
#define GN 1024
#define GI 1024
#define GM 8192

#define KSPLIT 4608          // GK/2
#define NTK 72               // KSPLIT/64 K-tiles per block (even -> unroll-2 ok)

#define BS_BLK 32768   // basis+silu: 8192*1024 threads (1 per x)
#define RP_BLK 4608    // repack   : 1024*1152 threads (8 cols each)

#define SB __builtin_amdgcn_sched_barrier(0)

__device__ __forceinline__ void cp16(const __hip_bfloat16* g, __hip_bfloat16* l) {
  __builtin_amdgcn_global_load_lds((const __attribute__((address_space(1))) void*)g,
                                   (__attribute__((address_space(3))) void*)l, 16, 0, 0);
}

__device__ __forceinline__ uint32_t bfbits(float f) {   // RTNE bf16 bits, SSA only
  __hip_bfloat16 h = __float2bfloat16(f);
  unsigned short us;
  __builtin_memcpy(&us, &h, 2);
  return (uint32_t)us;
}

__device__ __forceinline__ void basis4(float xv, int& jj, float& w0, float& w1,
                                       float& w2, float& w3) {
  float t = fminf(1.f, fmaxf(-1.f, xv));
  float us = (t + 1.f) * 2.5f;          // (t - grid[3]) / h, grid[3]=-1, h=0.4
  int j = (int)us;
  if (j > 4) j = 4;                     // t==1.0 edge: matches reference exactly
  float u = us - (float)j;
  float u2 = u * u, u3 = u2 * u;
  float om = 1.f - u;
  jj = j;
  w0 = om * om * om * (1.f / 6.f);
  w1 = (3.f * u3 - 6.f * u2 + 4.f) * (1.f / 6.f);
  w2 = (-3.f * u3 + 3.f * u2 + 3.f * u + 1.f) * (1.f / 6.f);
  w3 = u3 * (1.f / 6.f);
}

// --- ONE dispatch: basis+silu (1 thread/x) + weight repack -----------------
__global__ void kan_prep_all(const float* __restrict__ x,
                             const float* __restrict__ baseW,
                             const float* __restrict__ splineW,
                             __hip_bfloat16* __restrict__ W2,
                             __hip_bfloat16* __restrict__ A) {
  int bid = blockIdx.x;
  if (bid < BS_BLK) {
    int t = bid * 256 + threadIdx.x;        // [0, 8192*1024)
    int b = t >> 10, i = t & 1023;
    float xv = x[t];

    float sl = xv / (1.f + __expf(-xv));
    A[(size_t)b * GK + 8192 + i] = __float2bfloat16(sl);

    int jj; float w0, w1, w2, w3;
    basis4(xv, jj, w0, w1, w2, w3);
    uint64_t W64 = (uint64_t)(bfbits(w0) | (bfbits(w1) << 16)) |
                   ((uint64_t)(bfbits(w2) | (bfbits(w3) << 16)) << 32);
    int sh = jj * 16;                                  // 0,16,32,48,64
    uint64_t lo = (jj < 4) ? (W64 << sh) : 0ull;       // guard UB at sh=64
    uint64_t hi = (jj == 0) ? 0ull : (W64 >> (64 - sh));
    uint4 pk;
    pk.x = (uint32_t)lo;  pk.y = (uint32_t)(lo >> 32);
    pk.z = (uint32_t)hi;  pk.w = (uint32_t)(hi >> 32);
    *(uint4*)(A + (size_t)b * GK + (size_t)i * 8) = pk;
  } else {
    int t = (bid - BS_BLK) * 256 + threadIdx.x;   // [0, 1024*1152)
    int o = t / 1152;
    int c = (t - o * 1152) * 8;
    const float* src = (c < 8192) ? (splineW + (size_t)o * 8192 + c)
                                  : (baseW + (size_t)o * GI + (c - 8192));
    float4 v0 = ((const float4*)src)[0];
    float4 v1 = ((const float4*)src)[1];
    uint4 pk;
    pk.x = bfbits(v0.x) | (bfbits(v0.y) << 16);
    pk.y = bfbits(v0.z) | (bfbits(v0.w) << 16);
    pk.z = bfbits(v1.x) | (bfbits(v1.y) << 16);
    pk.w = bfbits(v1.z) | (bfbits(v1.w) << 16);
    *(uint4*)(W2 + (size_t)o * GK + c) = pk;
  }
}

// --- R21 GEMM: 256x256, BK=64, pipelined phases + cross-boundary prefetch --
__global__ __launch_bounds__(512, 2) void kan_gemm_pl(
    const __hip_bfloat16* __restrict__ A,   // (8192, 9216) bf16
    const __hip_bfloat16* __restrict__ B,   // (1024, 9216) bf16
    float* __restrict__ C0,                 // ksplit 0 -> out
    float* __restrict__ C1) {               // ksplit 1 -> partial
  __shared__ __align__(16) __hip_bfloat16 As[2][16384];   // 2 x 256r x 64k = 64 KB
  __shared__ __align__(16) __hip_bfloat16 Bs[2][16384];   // 64 KB
  const int tid = threadIdx.x;
  const int lane = tid & 63;
  const int wave = tid >> 6;                 // 0..7
  const int wm = wave >> 2, wn = wave & 3;   // 2x4 waves, 128x64 out each

  // XCD swizzle, 256 WGs: xcd = linear%8 -> 32 consecutive c's
  const int linear = blockIdx.x;                        // 0..255
  const int c = (linear & 7) * 32 + (linear >> 3);
  const int ks = c >> 7;
  const int cc = c & 127;
  const int colBand = cc & 3;
  const int rowBand = cc >> 2;               // 0..31
  const int blockRow = rowBand * 256;
  const int blockCol = colBand * 256;
  const int kbase = ks * KSPLIT;

  // staging: per cp16-unit, 512 thr x 16 B = 16 KB = 64 rows x 64 k, linear
  // LDS. 8-slot octet swizzle on the GLOBAL side (R20-verified, conflicts=0).
  const int srow8 = tid >> 3;                // 0..63
  const int so = tid & 7;
  const int ssw = so ^ (srow8 & 7);
  const __hip_bfloat16* aSrc = A + (size_t)(blockRow + srow8) * GK + kbase + ssw * 8;
  const __hip_bfloat16* bSrc = B + (size_t)(blockCol + srow8) * GK + kbase + ssw * 8;
  const int ldsW = wave * 512;               // wave-uniform; HW adds lane*16 B

#define STAGE_AU(U, T, NB) cp16(aSrc + (size_t)(U) * 64 * GK + (size_t)(T) * 64, \
                                As[NB] + (U) * 4096 + ldsW)
#define STAGE_BU(U, T, NB) cp16(bSrc + (size_t)(U) * 64 * GK + (size_t)(T) * 64, \
                                Bs[NB] + (U) * 4096 + ldsW)

  const int q = lane >> 4, r16 = lane & 15;
  const int swz = r16 & 7;
  const int s0 = q ^ swz;                    // kk=0 slot
  const int s1 = (4 + q) ^ swz;              // kk=1 slot
  const int aBase0 = (wm * 128 + r16) * 8 + s0;
  const int aBase1 = (wm * 128 + r16) * 8 + s1;
  const int bBase0 = (wn * 64 + r16) * 8 + s0;
  const int bBase1 = (wn * 64 + r16) * 8 + s1;

  f32x4 acc[8][4] = {};
  s16x8 b0A[4], b0B[4], b1[4], aA[4], aB[4];

  // dep-distance-8 MFMA groups. Halves: H0 = kk0 (AR[0],AR[2] x B0),
  // H1 = kk1 (AR[1],AR[3] x b1).
#define MHALF0(P, AR, B0)                                                     \
  do {                                                                        \
    __builtin_amdgcn_s_setprio(1);                                            \
    _Pragma("unroll")                                                         \
    for (int n = 0; n < 4; ++n)                                               \
      acc[2*(P)][n]   = __builtin_amdgcn_mfma_f32_16x16x32_bf16(AR[0], B0[n], acc[2*(P)][n],   0, 0, 0); \
    _Pragma("unroll")                                                         \
    for (int n = 0; n < 4; ++n)                                               \
      acc[2*(P)+1][n] = __builtin_amdgcn_mfma_f32_16x16x32_bf16(AR[2], B0[n], acc[2*(P)+1][n], 0, 0, 0); \
    __builtin_amdgcn_s_setprio(0);                                            \
  } while (0)
#define MHALF1(P, AR)                                                         \
  do {                                                                        \
    __builtin_amdgcn_s_setprio(1);                                            \
    _Pragma("unroll")                                                         \
    for (int n = 0; n < 4; ++n)                                               \
      acc[2*(P)][n]   = __builtin_amdgcn_mfma_f32_16x16x32_bf16(AR[1], b1[n], acc[2*(P)][n],   0, 0, 0); \
    _Pragma("unroll")                                                         \
    for (int n = 0; n < 4; ++n)                                               \
      acc[2*(P)+1][n] = __builtin_amdgcn_mfma_f32_16x16x32_bf16(AR[3], b1[n], acc[2*(P)+1][n], 0, 0, 0); \
    __builtin_amdgcn_s_setprio(0);                                            \
  } while (0)
#define MPAIR(P, AR, B0) do { MHALF0(P, AR, B0); MHALF1(P, AR); } while (0)

  // TILE(T): reads buf CB (tile T); B0C = this tile's prefetched b0 set;
  // B0N = set to prefetch for tile T+1 (from buf CB^1) during phase 3.
#define TILE(T, CB, B0C, B0N)                                                 \
  do {                                                                        \
    const int tp = ((T) + 1 < NTK) ? (T) + 1 : 0;                             \
    const s16x8* Af  = (const s16x8*)As[CB];                                  \
    const s16x8* Bf  = (const s16x8*)Bs[CB];                                  \
    const s16x8* BfN = (const s16x8*)Bs[(CB) ^ 1];                            \
    /* phase 0: issue A01, b1, A23; all 8 stages; lgkm(8); H0 of P0 */        \
    aA[0] = Af[aBase0];        aA[1] = Af[aBase1];                            \
    aA[2] = Af[aBase0 + 128];  aA[3] = Af[aBase1 + 128];                      \
    SB;                                                                       \
    _Pragma("unroll")                                                         \
    for (int n = 0; n < 4; ++n) b1[n] = Bf[bBase1 + n * 128];                 \
    SB;                                                                       \
    aB[0] = Af[aBase0 + 256];  aB[1] = Af[aBase1 + 256];                      \
    aB[2] = Af[aBase0 + 384];  aB[3] = Af[aBase1 + 384];                      \
    SB;                                                                       \
    STAGE_AU(0, tp, (CB)^1); STAGE_AU(1, tp, (CB)^1);                         \
    STAGE_AU(2, tp, (CB)^1); STAGE_AU(3, tp, (CB)^1);                         \
    STAGE_BU(0, tp, (CB)^1); STAGE_BU(1, tp, (CB)^1);                         \
    STAGE_BU(2, tp, (CB)^1); STAGE_BU(3, tp, (CB)^1);                         \
    SB;                                                                       \
    asm volatile("s_waitcnt lgkmcnt(8)" ::: "memory");  /* b0C + A01 in */    \
    SB;                                                                       \
    MHALF0(0, aA, B0C);                                                       \
    SB;                                                                       \
    asm volatile("s_waitcnt lgkmcnt(4)" ::: "memory");  /* b1 in (A23 out) */ \
    SB;                                                                       \
    MHALF1(0, aA);                                                            \
    SB;                                                                       \
    /* phase 1: issue A45; lgkm(4) -> A23; MPAIR1 */                          \
    aA[0] = Af[aBase0 + 512];  aA[1] = Af[aBase1 + 512];                      \
    aA[2] = Af[aBase0 + 640];  aA[3] = Af[aBase1 + 640];                      \
    SB;                                                                       \
    asm volatile("s_waitcnt lgkmcnt(4)" ::: "memory");                        \
    SB;                                                                       \
    MPAIR(1, aB, B0C);                                                        \
    SB;                                                                       \
    /* phase 2: issue A67; lgkm(4) -> A45; MPAIR2 */                          \
    aB[0] = Af[aBase0 + 768];  aB[1] = Af[aBase1 + 768];                      \
    aB[2] = Af[aBase0 + 896];  aB[3] = Af[aBase1 + 896];                      \
    SB;                                                                       \
    asm volatile("s_waitcnt lgkmcnt(4)" ::: "memory");                        \
    SB;                                                                       \
    MPAIR(2, aA, B0C);                                                        \
    SB;                                                                       \
    /* boundary (end of phase 2): reads retired + t+1 staged, all-waves */    \
    asm volatile("s_waitcnt lgkmcnt(0) vmcnt(0)" ::: "memory");               \
    SB;                                                                       \
    __builtin_amdgcn_s_barrier();                                             \
    SB;                                                                       \
    /* phase 3: prefetch next b0 from buf CB^1 under MPAIR3 */                \
    _Pragma("unroll")                                                         \
    for (int n = 0; n < 4; ++n) B0N[n] = BfN[bBase0 + n * 128];               \
    SB;                                                                       \
    MPAIR(3, aB, B0C);                                                        \
    SB;                                                                       \
  } while (0)

  // prologue: stage K-tile 0 into buf 0, drain, barrier, prefetch b0(tile 0)
  STAGE_AU(0, 0, 0); STAGE_AU(1, 0, 0); STAGE_AU(2, 0, 0); STAGE_AU(3, 0, 0);
  STAGE_BU(0, 0, 0); STAGE_BU(1, 0, 0); STAGE_BU(2, 0, 0); STAGE_BU(3, 0, 0);
  asm volatile("s_waitcnt vmcnt(0)" ::: "memory");
  SB;
  __builtin_amdgcn_s_barrier();
  SB;
  {
    const s16x8* Bf0 = (const s16x8*)Bs[0];
#pragma unroll
    for (int n = 0; n < 4; ++n) b0A[n] = Bf0[bBase0 + n * 128];
  }
  SB;

  for (int t2 = 0; t2 < NTK; t2 += 2) {
    TILE(t2,     0, b0A, b0B);
    TILE(t2 + 1, 1, b0B, b0A);
  }
  // drain tail prefetch reads + restage cp16s
  asm volatile("s_waitcnt lgkmcnt(0) vmcnt(0)" ::: "memory");

  float* __restrict__ Cd = ks ? C1 : C0;
  // C/D layout: col = lane&15, row = (lane>>4)*4 + reg  [m89-verified]
  const int cRow0 = blockRow + wm * 128 + q * 4;
  const int cCol0 = blockCol + wn * 64 + r16;
#pragma unroll
  for (int tm = 0; tm < 8; ++tm)
#pragma unroll
    for (int tn = 0; tn < 4; ++tn) {
      int col = cCol0 + tn * 16;
      size_t base = (size_t)(cRow0 + tm * 16) * GN + col;
#pragma unroll
      for (int r = 0; r < 4; ++r)
        Cd[base + (size_t)r * GN] = acc[tm][tn][r];
    }
#undef TILE
#undef MPAIR
#undef MHALF0
#undef MHALF1
#undef STAGE_AU
#undef STAGE_BU
}

// --- reduce: out += partial (both fp32, 8192x1024) -------------------------
__global__ void kan_reduce(float* __restrict__ out, const float* __restrict__ part) {
  size_t i = ((size_t)blockIdx.x * 256 + threadIdx.x) * 4;
  float4 a = *(const float4*)(out + i);
  float4 b = *(const float4*)(part + i);
  a.x += b.x; a.y += b.y; a.z += b.z; a.w += b.w;
  *(float4*)(out + i) = a;
}

// --- emergency fallback if ws_size is too small ----------------------------
__global__ void kan_naive(const float* __restrict__ x,
                          const float* __restrict__ bw,
                          const float* __restrict__ sw,
                          float* __restrict__ out) {
  int o = blockIdx.x * 256 + threadIdx.x;
  int b = blockIdx.y;
  float acc = 0.f;
  for (int i = 0; i < GI; ++i) {
    float xv = x[(size_t)b * GI + i];
    float sl = xv / (1.f + __expf(-xv));
    acc += sl * bw[(size_t)o * GI + i];
    int jj; float w0, w1, w2, w3;
    basis4(xv, jj, w0, w1, w2, w3);
    const float* swr = sw + ((size_t)o * GI + i) * 8 + jj;
    acc += w0 * swr[0] + w1 * swr[1] + w2 * swr[2] + w3 * swr[3];
  }
  out[(size_t)b * GN + o] = acc;
}

extern "C" void kernel_launch(void* const* d_in, const int* in_sizes, int n_in,
                              void* d_out, int out_size, void* d_ws, size_t ws_size,
                              hipStream_t stream) {
  const float* x  = (const float*)d_in[0];   // (8192, 1024) fp32
  const float* bw = (const float*)d_in[1];   // (1024, 1024) fp32
  const float* sw = (const float*)d_in[2];   // (1024, 1024, 8) fp32
  float* out = (float*)d_out;                // (8192, 1024) fp32

  const size_t wBytes = (size_t)GK * GN * 2;   // 18.9 MB repacked weights
  const size_t aBytes = (size_t)GM * GK * 2;   // 151 MB activations
  const size_t pBytes = (size_t)GM * GN * 4;   // 33.6 MB split-K partial

  if (ws_size < wBytes + aBytes + pBytes) {
    kan_naive<<<dim3(GN / 256, GM), 256, 0, stream>>>(x, bw, sw, out);
    return;
  }

  __hip_bfloat16* W2 = (__hip_bfloat16*)d_ws;
  __hip_bfloat16* Abuf = W2 + (size_t)GK * GN;       // 16B-aligned
  float* partial = (float*)((char*)d_ws + wBytes + aBytes);

  kan_prep_all<<<BS_BLK + RP_BLK, 256, 0, stream>>>(x, bw, sw, W2, Abuf);
  kan_gemm_pl<<<dim3(256), 512, 0, stream>>>(Abuf, W2, out, partial);
  kan_reduce<<<GM * GN / (256 * 4), 256, 0, stream>>>(out, partial);
}